// Round 5
// baseline (187.495 us; speedup 1.0000x reference)
//
#include <hip/hip_runtime.h>

#define N_TRACES 128
#define TLEN 32
#define IN_DIM 64
#define HID 128
#define G4 (4 * HID)            // 512 gate rows
#define BATCH (N_TRACES * TLEN) // 4096

// ---------- device helpers ----------

__device__ __forceinline__ float fast_sigmoid(float x) {
    return 1.0f / (1.0f + __expf(-x));
}
// tanh(x) = 1 - 2/(e^{2x}+1): stable at both extremes
__device__ __forceinline__ float fast_tanh(float x) {
    return 1.0f - 2.0f / (__expf(2.0f * x) + 1.0f);
}
// sum across 4 lanes of a quad, result in all 4 lanes
__device__ __forceinline__ float quad_reduce(float x) {
    x += __int_as_float(__builtin_amdgcn_update_dpp(
        0, __float_as_int(x), 0xB1 /*quad_perm [1,0,3,2]*/, 0xF, 0xF, true));
    x += __int_as_float(__builtin_amdgcn_update_dpp(
        0, __float_as_int(x), 0x4E /*quad_perm [2,3,0,1]*/, 0xF, 0xF, true));
    return x;
}
// sum across an aligned 8-lane group; result valid on lanes with (lane&7)<4
// (we consume it at s==0). quad_perm xor1/xor2, then row_shl:4 (lane i <- i+4).
__device__ __forceinline__ float reduce8(float x) {
    x += __int_as_float(__builtin_amdgcn_update_dpp(
        0, __float_as_int(x), 0xB1, 0xF, 0xF, true));
    x += __int_as_float(__builtin_amdgcn_update_dpp(
        0, __float_as_int(x), 0x4E, 0xF, 0xF, true));
    x += __int_as_float(__builtin_amdgcn_update_dpp(
        0, __float_as_int(x), 0x104 /*row_shl:4*/, 0xF, 0xF, true));
    return x;
}

// LDS word offset of k-slice s (16 words) under padding p(k)=k+4*(k>>5):
// {0,16,36,52,72,88,108,124} -> distinct banks mod 32, 16B-aligned.
__device__ __forceinline__ int slice_off(int s) { return 16 * s + 4 * (s >> 1); }

// load 4 gate rows {u+128i}, k-slice [16s,16s+16) into 64 VGPRs.
// 64 regs + ~50 temps fits the default 4-waves/EU 128-VGPR budget, so the
// allocator keeps them arch-resident (the r2-r4 128-reg variant was silently
// parked in AGPRs -> 1 extra move per FMA; VGPR_Count=88 was the tell).
__device__ __forceinline__ void load_w8(const float* __restrict__ W, int u, int s,
                                        float (&w)[4][16]) {
    #pragma unroll
    for (int i = 0; i < 4; ++i) {
        const float* wr = W + (size_t)(u + 128 * i) * HID + 16 * s;
        #pragma unroll
        for (int j = 0; j < 4; ++j) {
            float4 v = *(const float4*)(wr + 4 * j);
            w[i][4 * j + 0] = v.x; w[i][4 * j + 1] = v.y;
            w[i][4 * j + 2] = v.z; w[i][4 * j + 3] = v.w;
        }
    }
    #pragma unroll
    for (int i = 0; i < 4; ++i)
        #pragma unroll
        for (int j = 0; j < 16; ++j)
            asm volatile("" : "+v"(w[i][j]));
}

// acc[i] += dot(w[i][:], hb[0:16]) ; hb 16B-aligned
__device__ __forceinline__ void matvec8(const float (&w)[4][16],
                                        const float* hb, float (&acc)[4]) {
    #pragma unroll
    for (int j = 0; j < 4; ++j) {
        float4 v = *(const float4*)(hb + 4 * j);
        float hx[4] = {v.x, v.y, v.z, v.w};
        #pragma unroll
        for (int e = 0; e < 4; ++e) {
            #pragma unroll
            for (int i = 0; i < 4; ++i)
                acc[i] = fmaf(w[i][4 * j + e], hx[e], acc[i]);
        }
    }
}

// ---------- input GEMM: out[M][512] = A[M][64] * W[512][64]^T + b1 + b2 ----------

template <int K>
__global__ __launch_bounds__(256) void gemm_bt(
    const float* __restrict__ A,
    const float* __restrict__ W,
    const float* __restrict__ b1,
    const float* __restrict__ b2,
    float* __restrict__ out,
    int Nld)
{
    constexpr int LD = 68;
    __shared__ float At[K][LD];
    __shared__ float Wt[K][LD];

    const int tid = threadIdx.x;
    const int m0 = blockIdx.x * 64;
    const int n0 = blockIdx.y * 64;

    const int rot = tid & 3;
    #pragma unroll
    for (int j = 0; j < K / 16; ++j) {
        const int e = 4 * (tid + 256 * j);
        const int row = e / K;
        const int k = e % K;
        float4 va = *(const float4*)(A + (size_t)(m0 + row) * K + k);
        float4 vw = *(const float4*)(W + (size_t)(n0 + row) * K + k);
        float fa[4] = {va.x, va.y, va.z, va.w};
        float fw[4] = {vw.x, vw.y, vw.z, vw.w};
        #pragma unroll
        for (int ii = 0; ii < 4; ++ii) {
            const int i = (ii + rot) & 3;
            At[k + i][row] = fa[i];
            Wt[k + i][row] = fw[i];
        }
    }
    __syncthreads();

    const int tx = tid & 15;
    const int ty = tid >> 4;
    float acc[4][4] = {};

    #pragma unroll 4
    for (int k = 0; k < K; ++k) {
        float4 a = *(const float4*)&At[k][ty * 4];
        float4 w = *(const float4*)&Wt[k][tx * 4];
        acc[0][0] = fmaf(a.x, w.x, acc[0][0]); acc[0][1] = fmaf(a.x, w.y, acc[0][1]);
        acc[0][2] = fmaf(a.x, w.z, acc[0][2]); acc[0][3] = fmaf(a.x, w.w, acc[0][3]);
        acc[1][0] = fmaf(a.y, w.x, acc[1][0]); acc[1][1] = fmaf(a.y, w.y, acc[1][1]);
        acc[1][2] = fmaf(a.y, w.z, acc[1][2]); acc[1][3] = fmaf(a.y, w.w, acc[1][3]);
        acc[2][0] = fmaf(a.z, w.x, acc[2][0]); acc[2][1] = fmaf(a.z, w.y, acc[2][1]);
        acc[2][2] = fmaf(a.z, w.z, acc[2][2]); acc[2][3] = fmaf(a.z, w.w, acc[2][3]);
        acc[3][0] = fmaf(a.w, w.x, acc[3][0]); acc[3][1] = fmaf(a.w, w.y, acc[3][1]);
        acc[3][2] = fmaf(a.w, w.z, acc[3][2]); acc[3][3] = fmaf(a.w, w.w, acc[3][3]);
    }

    float bb[4];
    #pragma unroll
    for (int j = 0; j < 4; ++j) {
        const int n = n0 + tx * 4 + j;
        bb[j] = b1[n] + b2[n];
    }
    #pragma unroll
    for (int i = 0; i < 4; ++i) {
        const int m = m0 + ty * 4 + i;
        float4 v;
        v.x = acc[i][0] + bb[0]; v.y = acc[i][1] + bb[1];
        v.z = acc[i][2] + bb[2]; v.w = acc[i][3] + bb[3];
        *(float4*)(out + (size_t)m * Nld + n0 + tx * 4) = v;
    }
}

// ---------- fused per-trace kernel, 1024 threads ----------
// Thread (u=tid>>3, s=tid&7) owns gate rows {u+128i}, k-slice [16s,16s+16).
// 16 waves/WG = 4 waves/SIMD: deep latency hiding; 64-reg weight slice stays
// in arch VGPRs under the default 128-VGPR budget.

__global__ __launch_bounds__(1024, 4) void fused_trace(
    const float* __restrict__ xproj0, // [4096][512] (incl. both layer-0 biases)
    const float* __restrict__ Whh0,   // [512][128]
    const float* __restrict__ Wih1,   // [512][128]
    const float* __restrict__ bih1,   // [512]
    const float* __restrict__ bhh1,   // [512]
    const float* __restrict__ Whh1,   // [512][128]
    const float* __restrict__ Wlin,   // [128]
    const float* __restrict__ blin,   // [1]
    float* __restrict__ y)            // [4096]
{
    const int trace = blockIdx.x;
    const int tid = threadIdx.x;
    const int u = tid >> 3;
    const int s = tid & 7;
    const int pu = u + 4 * (u >> 5);   // padded word index for unit u
    const int soff = slice_off(s);

    __shared__ float hs[TLEN][140];    // h1 then h2, padded (p(127)=139)
    __shared__ float xp1[TLEN][G4];    // layer-1 input projection

    float w[4][16];

    // ===== Phase B: layer-0 recurrence =====
    load_w8(Whh0, u, s, w);
    const float* xpb = xproj0 + (size_t)trace * TLEN * G4;
    float xp[4] = {0.f, 0.f, 0.f, 0.f};
    if (s == 0) {
        #pragma unroll
        for (int i = 0; i < 4; ++i) xp[i] = xpb[u + 128 * i];
    }
    float c = 0.0f;
    #pragma unroll 1
    for (int t = 0; t < TLEN; ++t) {
        float acc[4] = {0.f, 0.f, 0.f, 0.f};
        if (t > 0) matvec8(w, &hs[t - 1][soff], acc);

        float xn[4] = {0.f, 0.f, 0.f, 0.f};
        if (s == 0 && t + 1 < TLEN) {
            #pragma unroll
            for (int i = 0; i < 4; ++i) xn[i] = xpb[(t + 1) * G4 + u + 128 * i];
        }
        #pragma unroll
        for (int i = 0; i < 4; ++i) acc[i] = reduce8(acc[i]);

        if (s == 0) {
            const float iv = fast_sigmoid(acc[0] + xp[0]);
            const float fv = fast_sigmoid(acc[1] + xp[1]);
            const float gv = fast_tanh(acc[2] + xp[2]);
            const float ov = fast_sigmoid(acc[3] + xp[3]);
            c = fv * c + iv * gv;
            hs[t][pu] = ov * fast_tanh(c);
            xp[0] = xn[0]; xp[1] = xn[1]; xp[2] = xn[2]; xp[3] = xn[3];
        }
        __syncthreads();
    }

    // ===== Phase C: xp1[t] = W_ih1 @ h1(t) + b_ih1 + b_hh1 (no per-t barrier) =====
    load_w8(Wih1, u, s, w);
    float bi[4] = {0.f, 0.f, 0.f, 0.f};
    if (s == 0) {
        #pragma unroll
        for (int i = 0; i < 4; ++i) bi[i] = bih1[u + 128 * i] + bhh1[u + 128 * i];
    }
    #pragma unroll 1
    for (int t = 0; t < TLEN; ++t) {
        float acc[4] = {0.f, 0.f, 0.f, 0.f};
        matvec8(w, &hs[t][soff], acc);
        #pragma unroll
        for (int i = 0; i < 4; ++i) acc[i] = reduce8(acc[i]);
        if (s == 0) {
            #pragma unroll
            for (int i = 0; i < 4; ++i) xp1[t][u + 128 * i] = acc[i] + bi[i];
        }
    }
    __syncthreads();

    // ===== Phase D: layer-1 recurrence (h2 overwrites hs) =====
    load_w8(Whh1, u, s, w);
    c = 0.0f;
    #pragma unroll 1
    for (int t = 0; t < TLEN; ++t) {
        float acc[4] = {0.f, 0.f, 0.f, 0.f};
        if (t > 0) matvec8(w, &hs[t - 1][soff], acc);
        #pragma unroll
        for (int i = 0; i < 4; ++i) acc[i] = reduce8(acc[i]);

        if (s == 0) {
            const float iv = fast_sigmoid(acc[0] + xp1[t][u]);
            const float fv = fast_sigmoid(acc[1] + xp1[t][u + 128]);
            const float gv = fast_tanh(acc[2] + xp1[t][u + 256]);
            const float ov = fast_sigmoid(acc[3] + xp1[t][u + 384]);
            c = fv * c + iv * gv;
            hs[t][pu] = ov * fast_tanh(c);
        }
        __syncthreads();
    }

    // ===== Phase E: y[trace*32+t] = dot(h2(t), W_lin) + b_lin =====
    if (tid < 128) {
        const int tq = tid >> 2;
        const int sq = tid & 3;
        float wl[32];
        #pragma unroll
        for (int j = 0; j < 8; ++j) {
            float4 v = *(const float4*)(Wlin + 32 * sq + 4 * j);
            wl[4 * j + 0] = v.x; wl[4 * j + 1] = v.y;
            wl[4 * j + 2] = v.z; wl[4 * j + 3] = v.w;
        }
        const float* hb = &hs[tq][36 * sq];
        float a = 0.f;
        #pragma unroll
        for (int j = 0; j < 8; ++j) {
            float4 v = *(const float4*)(hb + 4 * j);
            a = fmaf(v.x, wl[4 * j + 0], a);
            a = fmaf(v.y, wl[4 * j + 1], a);
            a = fmaf(v.z, wl[4 * j + 2], a);
            a = fmaf(v.w, wl[4 * j + 3], a);
        }
        a = quad_reduce(a);
        if (sq == 0) y[trace * TLEN + tq] = a + blin[0];
    }
}

// ---------- launch ----------

extern "C" void kernel_launch(void* const* d_in, const int* in_sizes, int n_in,
                              void* d_out, int out_size, void* d_ws, size_t ws_size,
                              hipStream_t stream) {
    const float* input = (const float*)d_in[0];  // [4096][64]
    const float* W_ih0 = (const float*)d_in[1];  // [512][64]
    const float* W_hh0 = (const float*)d_in[2];  // [512][128]
    const float* b_ih0 = (const float*)d_in[3];  // [512]
    const float* b_hh0 = (const float*)d_in[4];  // [512]
    const float* W_ih1 = (const float*)d_in[5];  // [512][128]
    const float* W_hh1 = (const float*)d_in[6];  // [512][128]
    const float* b_ih1 = (const float*)d_in[7];  // [512]
    const float* b_hh1 = (const float*)d_in[8];  // [512]
    const float* W_lin = (const float*)d_in[9];  // [1][128]
    const float* b_lin = (const float*)d_in[10]; // [1]
    float* out = (float*)d_out;                  // [4096]

    float* xproj0 = (float*)d_ws; // [4096][512], 8 MB

    dim3 ggrid(BATCH / 64, G4 / 64); // (64, 8)

    // K1: xproj0 = input @ W_ih0^T + b_ih0 + b_hh0 (full-chip GEMM)
    gemm_bt<IN_DIM><<<ggrid, 256, 0, stream>>>(input, W_ih0, b_ih0, b_hh0, xproj0, G4);
    // K2: fused per-trace LSTM0 -> xproj1 -> LSTM1 -> linear readout
    fused_trace<<<N_TRACES, 1024, 0, stream>>>(xproj0, W_hh0, W_ih1, b_ih1, b_hh1,
                                               W_hh1, W_lin, b_lin, out);
}

// Round 6
// 167.950 us; speedup vs baseline: 1.1164x; 1.1164x over previous
//
#include <hip/hip_runtime.h>

#define N_TRACES 128
#define TLEN 32
#define IN_DIM 64
#define HID 128
#define G4 (4 * HID)            // 512 gate rows
#define BATCH (N_TRACES * TLEN) // 4096

// ---------- device helpers ----------

__device__ __forceinline__ float fast_sigmoid(float x) {
    return 1.0f / (1.0f + __expf(-x));
}
// tanh(x) = 1 - 2/(e^{2x}+1): stable at both extremes
__device__ __forceinline__ float fast_tanh(float x) {
    return 1.0f - 2.0f / (__expf(2.0f * x) + 1.0f);
}
// sum across the 4 lanes of a quad, result in all 4 lanes
__device__ __forceinline__ float quad_reduce(float x) {
    x += __int_as_float(__builtin_amdgcn_update_dpp(
        0, __float_as_int(x), 0xB1 /*quad_perm [1,0,3,2]*/, 0xF, 0xF, true));
    x += __int_as_float(__builtin_amdgcn_update_dpp(
        0, __float_as_int(x), 0x4E /*quad_perm [2,3,0,1]*/, 0xF, 0xF, true));
    return x;
}

// load 4 gate rows {u+128i}, k-slice [32s,32s+32) of a [512][128] matrix.
// These land in AGPRs (unified file) at VGPR_Count~88 — measured r2-r4: no
// scratch, no re-fetch, so that's fine. Pin kept to forbid rematerialization.
__device__ __forceinline__ void load_w(const float* __restrict__ W, int u, int s,
                                       float (&w)[4][32]) {
    #pragma unroll
    for (int i = 0; i < 4; ++i) {
        const float* wr = W + (size_t)(u + 128 * i) * HID + 32 * s;
        #pragma unroll
        for (int j = 0; j < 8; ++j) {
            float4 v = *(const float4*)(wr + 4 * j);
            w[i][4 * j + 0] = v.x; w[i][4 * j + 1] = v.y;
            w[i][4 * j + 2] = v.z; w[i][4 * j + 3] = v.w;
        }
    }
    #pragma unroll
    for (int i = 0; i < 4; ++i)
        #pragma unroll
        for (int j = 0; j < 32; ++j)
            asm volatile("" : "+v"(w[i][j]));
}

// acc[i] += dot(w[i][:], hb[0:32]) ; hb must be 16B aligned
__device__ __forceinline__ void matvec_acc(const float (&w)[4][32],
                                           const float* hb, float (&acc)[4]) {
    #pragma unroll
    for (int j = 0; j < 8; ++j) {
        float4 v = *(const float4*)(hb + 4 * j);
        float hx[4] = {v.x, v.y, v.z, v.w};
        #pragma unroll
        for (int e = 0; e < 4; ++e) {
            #pragma unroll
            for (int i = 0; i < 4; ++i)
                acc[i] = fmaf(w[i][4 * j + e], hx[e], acc[i]);
        }
    }
}

// ---------- input GEMM: out[M][512] = A[M][64] * W[512][64]^T + b1 + b2 ----------

template <int K>
__global__ __launch_bounds__(256) void gemm_bt(
    const float* __restrict__ A,
    const float* __restrict__ W,
    const float* __restrict__ b1,
    const float* __restrict__ b2,
    float* __restrict__ out,
    int Nld)
{
    constexpr int LD = 68;
    __shared__ float At[K][LD];
    __shared__ float Wt[K][LD];

    const int tid = threadIdx.x;
    const int m0 = blockIdx.x * 64;
    const int n0 = blockIdx.y * 64;

    const int rot = tid & 3;
    #pragma unroll
    for (int j = 0; j < K / 16; ++j) {
        const int e = 4 * (tid + 256 * j);
        const int row = e / K;
        const int k = e % K;
        float4 va = *(const float4*)(A + (size_t)(m0 + row) * K + k);
        float4 vw = *(const float4*)(W + (size_t)(n0 + row) * K + k);
        float fa[4] = {va.x, va.y, va.z, va.w};
        float fw[4] = {vw.x, vw.y, vw.z, vw.w};
        #pragma unroll
        for (int ii = 0; ii < 4; ++ii) {
            const int i = (ii + rot) & 3;
            At[k + i][row] = fa[i];
            Wt[k + i][row] = fw[i];
        }
    }
    __syncthreads();

    const int tx = tid & 15;
    const int ty = tid >> 4;
    float acc[4][4] = {};

    #pragma unroll 4
    for (int k = 0; k < K; ++k) {
        float4 a = *(const float4*)&At[k][ty * 4];
        float4 w = *(const float4*)&Wt[k][tx * 4];
        acc[0][0] = fmaf(a.x, w.x, acc[0][0]); acc[0][1] = fmaf(a.x, w.y, acc[0][1]);
        acc[0][2] = fmaf(a.x, w.z, acc[0][2]); acc[0][3] = fmaf(a.x, w.w, acc[0][3]);
        acc[1][0] = fmaf(a.y, w.x, acc[1][0]); acc[1][1] = fmaf(a.y, w.y, acc[1][1]);
        acc[1][2] = fmaf(a.y, w.z, acc[1][2]); acc[1][3] = fmaf(a.y, w.w, acc[1][3]);
        acc[2][0] = fmaf(a.z, w.x, acc[2][0]); acc[2][1] = fmaf(a.z, w.y, acc[2][1]);
        acc[2][2] = fmaf(a.z, w.z, acc[2][2]); acc[2][3] = fmaf(a.z, w.w, acc[2][3]);
        acc[3][0] = fmaf(a.w, w.x, acc[3][0]); acc[3][1] = fmaf(a.w, w.y, acc[3][1]);
        acc[3][2] = fmaf(a.w, w.z, acc[3][2]); acc[3][3] = fmaf(a.w, w.w, acc[3][3]);
    }

    float bb[4];
    #pragma unroll
    for (int j = 0; j < 4; ++j) {
        const int n = n0 + tx * 4 + j;
        bb[j] = b1[n] + b2[n];
    }
    #pragma unroll
    for (int i = 0; i < 4; ++i) {
        const int m = m0 + ty * 4 + i;
        float4 v;
        v.x = acc[i][0] + bb[0]; v.y = acc[i][1] + bb[1];
        v.z = acc[i][2] + bb[2]; v.w = acc[i][3] + bb[3];
        *(float4*)(out + (size_t)m * Nld + n0 + tx * 4) = v;
    }
}

// ---------- fused per-trace kernel (512 threads) ----------
// Thread (u=tid>>2, s=tid&3) owns gate rows {u+128i}, k-slice [32s,32s+32).
// KEY (r5 finding): xproj is LDS-resident. Preloading the trace's 64 KB of
// xproj0 up-front removes ALL global ops from the recurrence loops, so the
// compiler's `s_waitcnt vmcnt(0)` before each s_barrier no longer puts ~900cyc
// of HBM latency on every step's critical path. Phase C overwrites the same
// LDS buffer with xproj1 (phase B has fully consumed it; threads are aligned
// by the phase-B final barrier).

__global__ __launch_bounds__(512) void fused_trace(
    const float* __restrict__ xproj0, // [4096][512] (incl. both layer-0 biases)
    const float* __restrict__ Whh0,   // [512][128]
    const float* __restrict__ Wih1,   // [512][128]
    const float* __restrict__ bih1,   // [512]
    const float* __restrict__ bhh1,   // [512]
    const float* __restrict__ Whh1,   // [512][128]
    const float* __restrict__ Wlin,   // [128]
    const float* __restrict__ blin,   // [1]
    float* __restrict__ y)            // [4096]
{
    const int trace = blockIdx.x;
    const int tid = threadIdx.x;
    const int u = tid >> 2;
    const int s = tid & 3;
    const int pu = u + 4 * (u >> 5); // padded word index for unit u

    __shared__ float hs[TLEN][140];     // h1 then h2, padded (p(127)=139)
    __shared__ float xp[TLEN * G4];     // 64 KB: xproj0, then overwritten w/ xproj1

    float w[4][32];

    // ===== Preload xproj0 -> LDS (coalesced float4, conflict-free writes) =====
    const float* xpb = xproj0 + (size_t)trace * TLEN * G4;
    #pragma unroll
    for (int j = 0; j < 8; ++j) {
        const int f4 = j * 512 + tid;
        float4 v = *(const float4*)(xpb + 4 * f4);
        *(float4*)(&xp[4 * f4]) = v;
    }
    load_w(Whh0, u, s, w);
    __syncthreads();

    // ===== Phase B: layer-0 recurrence =====
    float c = 0.0f;
    #pragma unroll 1
    for (int t = 0; t < TLEN; ++t) {
        // xp gate values: quad-uniform addresses -> broadcast, banks u%32 (free)
        float xg[4];
        #pragma unroll
        for (int i = 0; i < 4; ++i) xg[i] = xp[t * G4 + 128 * i + u];

        float acc[4] = {0.f, 0.f, 0.f, 0.f};
        if (t > 0) matvec_acc(w, &hs[t - 1][36 * s], acc);
        #pragma unroll
        for (int i = 0; i < 4; ++i) acc[i] = quad_reduce(acc[i]);

        if (s == 0) {
            const float iv = fast_sigmoid(acc[0] + xg[0]);
            const float fv = fast_sigmoid(acc[1] + xg[1]);
            const float gv = fast_tanh(acc[2] + xg[2]);
            const float ov = fast_sigmoid(acc[3] + xg[3]);
            c = fv * c + iv * gv;
            hs[t][pu] = ov * fast_tanh(c);
        }
        __syncthreads();
    }

    // ===== Phase C: xp[t] = W_ih1 @ h1(t) + b_ih1 + b_hh1 (no per-t barrier) =====
    load_w(Wih1, u, s, w);
    float bi[4] = {0.f, 0.f, 0.f, 0.f};
    if (s == 0) {
        #pragma unroll
        for (int i = 0; i < 4; ++i) bi[i] = bih1[u + 128 * i] + bhh1[u + 128 * i];
    }
    #pragma unroll 1
    for (int t = 0; t < TLEN; ++t) {
        float acc[4] = {0.f, 0.f, 0.f, 0.f};
        matvec_acc(w, &hs[t][36 * s], acc);
        #pragma unroll
        for (int i = 0; i < 4; ++i) acc[i] = quad_reduce(acc[i]);
        if (s == 0) {
            #pragma unroll
            for (int i = 0; i < 4; ++i) xp[t * G4 + 128 * i + u] = acc[i] + bi[i];
        }
    }
    __syncthreads();

    // ===== Phase D: layer-1 recurrence (h2 overwrites hs) =====
    load_w(Whh1, u, s, w);
    c = 0.0f;
    #pragma unroll 1
    for (int t = 0; t < TLEN; ++t) {
        float xg[4];
        #pragma unroll
        for (int i = 0; i < 4; ++i) xg[i] = xp[t * G4 + 128 * i + u];

        float acc[4] = {0.f, 0.f, 0.f, 0.f};
        if (t > 0) matvec_acc(w, &hs[t - 1][36 * s], acc);
        #pragma unroll
        for (int i = 0; i < 4; ++i) acc[i] = quad_reduce(acc[i]);

        if (s == 0) {
            const float iv = fast_sigmoid(acc[0] + xg[0]);
            const float fv = fast_sigmoid(acc[1] + xg[1]);
            const float gv = fast_tanh(acc[2] + xg[2]);
            const float ov = fast_sigmoid(acc[3] + xg[3]);
            c = fv * c + iv * gv;
            hs[t][pu] = ov * fast_tanh(c);
        }
        __syncthreads();
    }

    // ===== Phase E: y[trace*32+t] = dot(h2(t), W_lin) + b_lin =====
    if (tid < 128) {
        const int tq = tid >> 2;
        const int sq = tid & 3;
        float wl[32];
        #pragma unroll
        for (int j = 0; j < 8; ++j) {
            float4 v = *(const float4*)(Wlin + 32 * sq + 4 * j);
            wl[4 * j + 0] = v.x; wl[4 * j + 1] = v.y;
            wl[4 * j + 2] = v.z; wl[4 * j + 3] = v.w;
        }
        const float* hb = &hs[tq][36 * sq];
        float a = 0.f;
        #pragma unroll
        for (int j = 0; j < 8; ++j) {
            float4 v = *(const float4*)(hb + 4 * j);
            a = fmaf(v.x, wl[4 * j + 0], a);
            a = fmaf(v.y, wl[4 * j + 1], a);
            a = fmaf(v.z, wl[4 * j + 2], a);
            a = fmaf(v.w, wl[4 * j + 3], a);
        }
        a = quad_reduce(a);
        if (sq == 0) y[trace * TLEN + tq] = a + blin[0];
    }
}

// ---------- launch ----------

extern "C" void kernel_launch(void* const* d_in, const int* in_sizes, int n_in,
                              void* d_out, int out_size, void* d_ws, size_t ws_size,
                              hipStream_t stream) {
    const float* input = (const float*)d_in[0];  // [4096][64]
    const float* W_ih0 = (const float*)d_in[1];  // [512][64]
    const float* W_hh0 = (const float*)d_in[2];  // [512][128]
    const float* b_ih0 = (const float*)d_in[3];  // [512]
    const float* b_hh0 = (const float*)d_in[4];  // [512]
    const float* W_ih1 = (const float*)d_in[5];  // [512][128]
    const float* W_hh1 = (const float*)d_in[6];  // [512][128]
    const float* b_ih1 = (const float*)d_in[7];  // [512]
    const float* b_hh1 = (const float*)d_in[8];  // [512]
    const float* W_lin = (const float*)d_in[9];  // [1][128]
    const float* b_lin = (const float*)d_in[10]; // [1]
    float* out = (float*)d_out;                  // [4096]

    float* xproj0 = (float*)d_ws; // [4096][512], 8 MB

    dim3 ggrid(BATCH / 64, G4 / 64); // (64, 8)

    // K1: xproj0 = input @ W_ih0^T + b_ih0 + b_hh0 (full-chip GEMM)
    gemm_bt<IN_DIM><<<ggrid, 256, 0, stream>>>(input, W_ih0, b_ih0, b_hh0, xproj0, G4);
    // K2: fused per-trace LSTM0 -> xproj1 -> LSTM1 -> linear readout
    fused_trace<<<N_TRACES, 512, 0, stream>>>(xproj0, W_hh0, W_ih1, b_ih1, b_hh1,
                                              W_hh1, W_lin, b_lin, out);
}